// Round 1
// baseline (1463.594 us; speedup 1.0000x reference)
//
#include <hip/hip_runtime.h>
#include <hip/hip_bf16.h>

#define NNODES 50000
#define MNBR 32
#define FDIM 64

// ---------------------------------------------------------------------------
// Kernel 1: precompute A[n][o] = W[o,0:64]·node[n] + b[o]   (o in 0..127)
//           and      B[n][o] = W[o,64:128]·node[n]          (o in 0..127)
// A, B each (N,128) f32 in workspace. 256 threads; 64 nodes per block.
// Thread t<128 computes A-col t; t>=128 computes B-col t-128.
// ---------------------------------------------------------------------------
__global__ __launch_bounds__(256) void precompute_ab(
    const float* __restrict__ node, const float* __restrict__ W,
    const float* __restrict__ b, float* __restrict__ A, float* __restrict__ B,
    int n_nodes)
{
    __shared__ float sN[64 * 64];  // 16 KB node tile
    const int t = threadIdx.x;
    const int n0 = blockIdx.x * 64;

    // stage node tile (coalesced)
    #pragma unroll
    for (int q = 0; q < 16; ++q) {
        int p = t + q * 256;           // 0..4095
        int i = p >> 6, k = p & 63;
        int n = n0 + i;
        sN[p] = (n < n_nodes) ? node[(size_t)n * FDIM + k] : 0.f;
    }
    __syncthreads();

    // W row for this column into registers
    float Wr[64];
    float bias;
    const float* wsrc;
    if (t < 128) { wsrc = W + (size_t)t * 192;              bias = b[t]; }
    else         { wsrc = W + (size_t)(t - 128) * 192 + 64; bias = 0.f;  }
    #pragma unroll
    for (int k = 0; k < 16; ++k) {
        float4 w = *reinterpret_cast<const float4*>(wsrc + 4 * k);
        Wr[4 * k + 0] = w.x; Wr[4 * k + 1] = w.y;
        Wr[4 * k + 2] = w.z; Wr[4 * k + 3] = w.w;
    }

    for (int i = 0; i < 64; ++i) {
        int n = n0 + i;
        if (n >= n_nodes) break;
        float acc = bias;
        #pragma unroll
        for (int k = 0; k < 64; ++k)
            acc = fmaf(Wr[k], sN[i * 64 + k], acc);
        if (t < 128) A[(size_t)n * 128 + t] = acc;
        else         B[(size_t)n * 128 + (t - 128)] = acc;
    }
}

// ---------------------------------------------------------------------------
// Kernel 2: fused per-node main loop. One wave (64 threads) per node,
// grid-stride. Lane f owns output feature f: computes gated[f] (filter)
// and gated[64+f] (core) per neighbor, accumulates sigmoid*softplus.
// W_edge rows kept in VGPRs; edge row is wave-uniform (scalar loads).
// ---------------------------------------------------------------------------
__device__ __forceinline__ float softplus_f(float x) {
    return fmaxf(x, 0.f) + log1pf(__expf(-fabsf(x)));
}

__global__ __launch_bounds__(64) void fused_main(
    const float* __restrict__ node, const float* __restrict__ edge,
    const int* __restrict__ eidx, const float* __restrict__ W,
    const float* __restrict__ A, const float* __restrict__ B,
    const float* __restrict__ alphap, float* __restrict__ out, int n_nodes)
{
    const int f = threadIdx.x;  // 0..63

    // W_edge rows for filter col f and core col f+64: W[o][128 + k]
    float Wf[64], Wc[64];
    {
        const float* wf = W + (size_t)f * 192 + 128;
        const float* wc = W + (size_t)(f + 64) * 192 + 128;
        #pragma unroll
        for (int k = 0; k < 16; ++k) {
            float4 a = *reinterpret_cast<const float4*>(wf + 4 * k);
            float4 c = *reinterpret_cast<const float4*>(wc + 4 * k);
            Wf[4 * k + 0] = a.x; Wf[4 * k + 1] = a.y;
            Wf[4 * k + 2] = a.z; Wf[4 * k + 3] = a.w;
            Wc[4 * k + 0] = c.x; Wc[4 * k + 1] = c.y;
            Wc[4 * k + 2] = c.z; Wc[4 * k + 3] = c.w;
        }
    }
    const float alpha = alphap[0];

    for (int n = blockIdx.x; n < n_nodes; n += gridDim.x) {
        const float af = A[(size_t)n * 128 + f];
        const float ac = A[(size_t)n * 128 + 64 + f];
        const float* erow = edge + (size_t)n * MNBR * FDIM;
        const int* irow = eidx + (size_t)n * MNBR;

        float acc = 0.f;
        for (int m = 0; m < MNBR; ++m) {
            int j = irow[m];          // wave-uniform
            if (j < 0) continue;      // masked edge: contributes 0

            float gf = af + B[(size_t)j * 128 + f];
            float gc = ac + B[(size_t)j * 128 + 64 + f];

            const float* e = erow + m * FDIM;  // wave-uniform row
            #pragma unroll
            for (int k = 0; k < 64; ++k) {
                float ek = e[k];
                gf = fmaf(Wf[k], ek, gf);
                gc = fmaf(Wc[k], ek, gc);
            }
            float filt = 1.f / (1.f + __expf(-gf));
            float core = softplus_f(gc);
            acc = fmaf(filt, core, acc);
        }
        float x = fmaf(alpha, node[(size_t)n * FDIM + f], acc);
        out[(size_t)n * FDIM + f] = softplus_f(x);
    }
}

extern "C" void kernel_launch(void* const* d_in, const int* in_sizes, int n_in,
                              void* d_out, int out_size, void* d_ws, size_t ws_size,
                              hipStream_t stream) {
    const float* node  = (const float*)d_in[0];
    const float* edge  = (const float*)d_in[1];
    const int*   eidx  = (const int*)d_in[2];
    const float* W     = (const float*)d_in[3];
    const float* b     = (const float*)d_in[4];
    const float* alpha = (const float*)d_in[5];
    float* out = (float*)d_out;

    const int n_nodes = in_sizes[0] / FDIM;  // 50000

    float* A = (float*)d_ws;                       // (N,128)
    float* B = A + (size_t)n_nodes * 128;          // (N,128)

    int grid1 = (n_nodes + 63) / 64;
    precompute_ab<<<grid1, 256, 0, stream>>>(node, W, b, A, B, n_nodes);

    fused_main<<<4096, 64, 0, stream>>>(node, edge, eidx, W, A, B, alpha, out,
                                        n_nodes);
}

// Round 2
// 771.068 us; speedup vs baseline: 1.8981x; 1.8981x over previous
//
#include <hip/hip_runtime.h>
#include <hip/hip_bf16.h>

#define MNBR 32
#define FDIM 64

typedef __attribute__((ext_vector_type(8))) short bf16x8;
typedef __attribute__((ext_vector_type(4))) float f32x4;
typedef __attribute__((ext_vector_type(4))) float fvec4;

static __device__ __forceinline__ unsigned short f2bf(float x) {
    unsigned u = __builtin_bit_cast(unsigned, x);
    u += 0x7FFFu + ((u >> 16) & 1u);   // RNE
    return (unsigned short)(u >> 16);
}
static __device__ __forceinline__ bf16x8 pack8(fvec4 a, fvec4 b) {
    bf16x8 r;
    r[0] = (short)f2bf(a[0]); r[1] = (short)f2bf(a[1]);
    r[2] = (short)f2bf(a[2]); r[3] = (short)f2bf(a[3]);
    r[4] = (short)f2bf(b[0]); r[5] = (short)f2bf(b[1]);
    r[6] = (short)f2bf(b[2]); r[7] = (short)f2bf(b[3]);
    return r;
}
static __device__ __forceinline__ float sigmoid_f(float x) {
    return __builtin_amdgcn_rcpf(1.f + __expf(-x));
}
static __device__ __forceinline__ float softplus_f(float x) {
    return fmaxf(x, 0.f) + __logf(1.f + __expf(-fabsf(x)));
}

// ---------------------------------------------------------------------------
// Kernel 1: A[n][o] = W[o,0:64]·node[n] + b[o], B[n][o] = W[o,64:128]·node[n]
// via bf16 MFMA. One wave per 16-node tile; 16 col-tiles (256 outputs) x 2 k.
// ---------------------------------------------------------------------------
__global__ __launch_bounds__(256) void precompute_ab_mfma(
    const float* __restrict__ node, const float* __restrict__ W,
    const float* __restrict__ b, float* __restrict__ A, float* __restrict__ B,
    int n_nodes)
{
    const int lane = threadIdx.x & 63;
    const int w    = threadIdx.x >> 6;
    const int rt   = blockIdx.x * 4 + w;           // 16-node row tile
    const int ntiles = (n_nodes + 15) / 16;        // 3125
    if (rt >= ntiles) return;
    const int c = lane & 15, g = lane >> 4;

    // A-frags: node rows (row = lane&15, k = g*8+j within each 32-k step)
    bf16x8 af[2];
    {
        const float* p = node + (size_t)(rt * 16 + c) * FDIM + g * 8;
        fvec4 e0 = *(const fvec4*)(p);
        fvec4 e1 = *(const fvec4*)(p + 4);
        fvec4 e2 = *(const fvec4*)(p + 32);
        fvec4 e3 = *(const fvec4*)(p + 36);
        af[0] = pack8(e0, e1);
        af[1] = pack8(e2, e3);
    }
    for (int t = 0; t < 16; ++t) {
        const int o = t * 16 + c;                  // 0..255 combined output col
        f32x4 acc = {0.f, 0.f, 0.f, 0.f};
        #pragma unroll
        for (int s = 0; s < 2; ++s) {
            const float* wp = (o < 128)
                ? W + (size_t)o * 192 + s * 32 + g * 8
                : W + (size_t)(o - 128) * 192 + 64 + s * 32 + g * 8;
            fvec4 w0 = *(const fvec4*)(wp);
            fvec4 w1 = *(const fvec4*)(wp + 4);
            bf16x8 bfr = pack8(w0, w1);
            acc = __builtin_amdgcn_mfma_f32_16x16x32_bf16(af[s], bfr, acc, 0, 0, 0);
        }
        const float bias = (o < 128) ? b[o] : 0.f;
        #pragma unroll
        for (int r = 0; r < 4; ++r) {              // D: row = g*4+r, col = c
            int n = rt * 16 + g * 4 + r;
            float v = acc[r] + bias;
            if (o < 128) A[(size_t)n * 128 + o] = v;
            else         B[(size_t)n * 128 + (o - 128)] = v;
        }
    }
}

// ---------------------------------------------------------------------------
// Kernel 2: per node, E(32x64) x W_edge^T(64x128) via MFMA; epilogue adds
// A[n] + B[j], sigmoid*softplus, masked sum over edges, final softplus.
// One wave per 2 nodes. Non-temporal edge loads (read-once stream).
// ---------------------------------------------------------------------------
__global__ __launch_bounds__(256) void edge_mfma(
    const float* __restrict__ node, const float* __restrict__ edge,
    const int* __restrict__ eidx, const float* __restrict__ W,
    const float* __restrict__ Atab, const float* __restrict__ Btab,
    const float* __restrict__ alphap, float* __restrict__ out, int n_nodes)
{
    const int lane = threadIdx.x & 63;
    const int w    = threadIdx.x >> 6;
    const int wid  = blockIdx.x * 4 + w;
    const int c = lane & 15, g = lane >> 4;
    const float alpha = alphap[0];

    // W_edge fragments: col-tile t (output o = t*16+c), k-step s.
    // B-frag: B[k][col], col = lane&15, k = g*8+j. Source W[o][128+k].
    bf16x8 Wf[8][2];
    #pragma unroll
    for (int t = 0; t < 8; ++t) {
        const float* wr = W + (size_t)(t * 16 + c) * 192 + 128 + g * 8;
        fvec4 w0 = *(const fvec4*)(wr);
        fvec4 w1 = *(const fvec4*)(wr + 4);
        fvec4 w2 = *(const fvec4*)(wr + 32);
        fvec4 w3 = *(const fvec4*)(wr + 36);
        Wf[t][0] = pack8(w0, w1);
        Wf[t][1] = pack8(w2, w3);
    }

    for (int nn = 0; nn < 2; ++nn) {
        const int n = wid * 2 + nn;
        if (n >= n_nodes) break;

        float a_f[8];
        #pragma unroll
        for (int t = 0; t < 8; ++t)
            a_f[t] = Atab[(size_t)n * 128 + t * 16 + c];

        float nsum[4] = {0.f, 0.f, 0.f, 0.f};

        #pragma unroll
        for (int half = 0; half < 2; ++half) {
            // edge A-frag: row = lane&15 (edge within tile), k = s*32 + g*8 + j
            bf16x8 ea[2];
            {
                const float* p = edge + ((size_t)n * MNBR + half * 16 + c) * FDIM + g * 8;
                fvec4 e0 = __builtin_nontemporal_load((const fvec4*)(p));
                fvec4 e1 = __builtin_nontemporal_load((const fvec4*)(p + 4));
                fvec4 e2 = __builtin_nontemporal_load((const fvec4*)(p + 32));
                fvec4 e3 = __builtin_nontemporal_load((const fvec4*)(p + 36));
                ea[0] = pack8(e0, e1);
                ea[1] = pack8(e2, e3);
            }
            f32x4 acc[8];
            #pragma unroll
            for (int t = 0; t < 8; ++t) acc[t] = (f32x4){0.f, 0.f, 0.f, 0.f};
            #pragma unroll
            for (int s = 0; s < 2; ++s)
                #pragma unroll
                for (int t = 0; t < 8; ++t)
                    acc[t] = __builtin_amdgcn_mfma_f32_16x16x32_bf16(ea[s], Wf[t][s], acc[t], 0, 0, 0);

            // this lane's 4 edge rows: m = half*16 + g*4 + r
            const int4 jv = *(const int4*)(eidx + (size_t)n * MNBR + half * 16 + g * 4);
            #pragma unroll
            for (int r = 0; r < 4; ++r) {
                const int j = (r == 0) ? jv.x : (r == 1) ? jv.y : (r == 2) ? jv.z : jv.w;
                if (j < 0) continue;               // masked edge contributes 0
                const float* bp = Btab + (size_t)j * 128 + c;
                #pragma unroll
                for (int t = 0; t < 4; ++t) {
                    float gf = acc[t][r]     + a_f[t]     + bp[t * 16];
                    float gc = acc[t + 4][r] + a_f[t + 4] + bp[t * 16 + 64];
                    nsum[t] += sigmoid_f(gf) * softplus_f(gc);
                }
            }
        }

        // reduce over the 4 row-groups (16 rows x 2 halves already in nsum)
        #pragma unroll
        for (int t = 0; t < 4; ++t) {
            nsum[t] += __shfl_xor(nsum[t], 16);
            nsum[t] += __shfl_xor(nsum[t], 32);
        }
        float v = nsum[0];
        v = (g == 1) ? nsum[1] : v;
        v = (g == 2) ? nsum[2] : v;
        v = (g == 3) ? nsum[3] : v;
        // lane's output feature o = g*16 + c = lane (coalesced)
        float x = fmaf(alpha, node[(size_t)n * FDIM + lane], v);
        out[(size_t)n * FDIM + lane] = softplus_f(x);
    }
}

extern "C" void kernel_launch(void* const* d_in, const int* in_sizes, int n_in,
                              void* d_out, int out_size, void* d_ws, size_t ws_size,
                              hipStream_t stream) {
    const float* node  = (const float*)d_in[0];
    const float* edge  = (const float*)d_in[1];
    const int*   eidx  = (const int*)d_in[2];
    const float* W     = (const float*)d_in[3];
    const float* b     = (const float*)d_in[4];
    const float* alpha = (const float*)d_in[5];
    float* out = (float*)d_out;

    const int n_nodes = in_sizes[0] / FDIM;        // 50000

    float* A = (float*)d_ws;                       // (N,128) f32
    float* B = A + (size_t)n_nodes * 128;          // (N,128) f32

    const int ntiles = (n_nodes + 15) / 16;        // 3125
    precompute_ab_mfma<<<(ntiles + 3) / 4, 256, 0, stream>>>(node, W, b, A, B, n_nodes);

    const int nwaves = (n_nodes + 1) / 2;          // 25000 (2 nodes/wave)
    edge_mfma<<<(nwaves + 3) / 4, 256, 0, stream>>>(node, edge, eidx, W, A, B,
                                                    alpha, out, n_nodes);
}